// Round 3
// baseline (172.530 us; speedup 1.0000x reference)
//
#include <hip/hip_runtime.h>

#define EPS_W 1e-6f

__global__ __launch_bounds__(256) void kabsch4x4_kernel(
    const float* __restrict__ A, const float* __restrict__ B,
    const float* __restrict__ W, float* __restrict__ Out,
    int bs, int n)
{
    const int b = blockIdx.x * blockDim.x + threadIdx.x;
    if (b >= bs) return;

    float sw = 0.f;
    float Sa0=0.f,Sa1=0.f,Sa2=0.f, Sb0=0.f,Sb1=0.f,Sb2=0.f;
    float M00=0.f,M01=0.f,M02=0.f,M10=0.f,M11=0.f,M12=0.f,M20=0.f,M21=0.f,M22=0.f;

    if ((n & 3) == 0) {
        // vectorized path: n multiple of 4 -> 3n floats of coords per batch is
        // a multiple of 4 floats (16B) and base offsets stay 16B-aligned.
        const float4* A4 = reinterpret_cast<const float4*>(A + (size_t)b * n * 3);
        const float4* B4 = reinterpret_cast<const float4*>(B + (size_t)b * n * 3);
        const float4* W4 = reinterpret_cast<const float4*>(W + (size_t)b * n);
        const int ng = n >> 2;
        for (int g = 0; g < ng; ++g) {
            float4 a0 = A4[3*g+0], a1 = A4[3*g+1], a2 = A4[3*g+2];
            float4 b0 = B4[3*g+0], b1 = B4[3*g+1], b2 = B4[3*g+2];
            float4 wv = W4[g];
            const float af[12] = {a0.x,a0.y,a0.z,a0.w, a1.x,a1.y,a1.z,a1.w, a2.x,a2.y,a2.z,a2.w};
            const float bf[12] = {b0.x,b0.y,b0.z,b0.w, b1.x,b1.y,b1.z,b1.w, b2.x,b2.y,b2.z,b2.w};
            const float wf[4]  = {wv.x,wv.y,wv.z,wv.w};
            #pragma unroll
            for (int k = 0; k < 4; ++k) {
                float w = wf[k] < 0.f ? 0.f : wf[k];
                float ax = af[3*k+0], ay = af[3*k+1], az = af[3*k+2];
                float bx = bf[3*k+0], by = bf[3*k+1], bz = bf[3*k+2];
                sw += w;
                float wax = w*ax, way = w*ay, waz = w*az;
                Sa0 += wax; Sa1 += way; Sa2 += waz;
                Sb0 += w*bx; Sb1 += w*by; Sb2 += w*bz;
                M00 += wax*bx; M01 += wax*by; M02 += wax*bz;
                M10 += way*bx; M11 += way*by; M12 += way*bz;
                M20 += waz*bx; M21 += waz*by; M22 += waz*bz;
            }
        }
    } else {
        for (int j = 0; j < n; ++j) {
            const float* ap = A + ((size_t)b * n + j) * 3;
            const float* bp = B + ((size_t)b * n + j) * 3;
            float w = W[(size_t)b * n + j];
            w = w < 0.f ? 0.f : w;
            float ax=ap[0], ay=ap[1], az=ap[2];
            float bx=bp[0], by=bp[1], bz=bp[2];
            sw += w;
            float wax = w*ax, way = w*ay, waz = w*az;
            Sa0 += wax; Sa1 += way; Sa2 += waz;
            Sb0 += w*bx; Sb1 += w*by; Sb2 += w*bz;
            M00 += wax*bx; M01 += wax*by; M02 += wax*bz;
            M10 += way*bx; M11 += way*by; M12 += way*bz;
            M20 += waz*bx; M21 += waz*by; M22 += waz*bz;
        }
    }

    const float inv = 1.f / (sw + EPS_W);
    const float cA0 = Sa0*inv, cA1 = Sa1*inv, cA2 = Sa2*inv;
    const float cB0 = Sb0*inv, cB1 = Sb1*inv, cB2 = Sb2*inv;

    // H_ij = sum w (a_i - cA_i)(b_j - cB_j)
    float H[3][3];
    H[0][0] = M00 - cA0*Sb0 - Sa0*cB0 + sw*cA0*cB0;
    H[0][1] = M01 - cA0*Sb1 - Sa0*cB1 + sw*cA0*cB1;
    H[0][2] = M02 - cA0*Sb2 - Sa0*cB2 + sw*cA0*cB2;
    H[1][0] = M10 - cA1*Sb0 - Sa1*cB0 + sw*cA1*cB0;
    H[1][1] = M11 - cA1*Sb1 - Sa1*cB1 + sw*cA1*cB1;
    H[1][2] = M12 - cA1*Sb2 - Sa1*cB2 + sw*cA1*cB2;
    H[2][0] = M20 - cA2*Sb0 - Sa2*cB0 + sw*cA2*cB0;
    H[2][1] = M21 - cA2*Sb1 - Sa2*cB1 + sw*cA2*cB1;
    H[2][2] = M22 - cA2*Sb2 - Sa2*cB2 + sw*cA2*cB2;

    // Horn's 4x4 symmetric matrix N from H
    const float Sxx=H[0][0], Sxy=H[0][1], Sxz=H[0][2];
    const float Syx=H[1][0], Syy=H[1][1], Syz=H[1][2];
    const float Szx=H[2][0], Szy=H[2][1], Szz=H[2][2];

    float Nm[4][4];
    Nm[0][0] =  Sxx+Syy+Szz; Nm[0][1] = Syz-Szy;      Nm[0][2] = Szx-Sxz;      Nm[0][3] = Sxy-Syx;
    Nm[1][0] =  Nm[0][1];    Nm[1][1] = Sxx-Syy-Szz;  Nm[1][2] = Sxy+Syx;      Nm[1][3] = Szx+Sxz;
    Nm[2][0] =  Nm[0][2];    Nm[2][1] = Nm[1][2];     Nm[2][2] = -Sxx+Syy-Szz; Nm[2][3] = Syz+Szy;
    Nm[3][0] =  Nm[0][3];    Nm[3][1] = Nm[1][3];     Nm[3][2] = Nm[2][3];     Nm[3][3] = -Sxx-Syy+Szz;

    float Vv[4][4] = {{1.f,0.f,0.f,0.f},{0.f,1.f,0.f,0.f},{0.f,0.f,1.f,0.f},{0.f,0.f,0.f,1.f}};

    // cyclic Jacobi eigendecomposition; pair indices compile-time (unrolled)
    for (int sweep = 0; sweep < 6; ++sweep) {
        #pragma unroll
        for (int pair = 0; pair < 6; ++pair) {
            constexpr int PP[6] = {0,0,0,1,1,2};
            constexpr int QQ[6] = {1,2,3,2,3,3};
            const int p = PP[pair], q = QQ[pair];
            float apq = Nm[p][q];
            float c, s;
            if (fabsf(apq) > 1e-20f) {
                float tau = (Nm[q][q] - Nm[p][p]) / (2.f * apq);
                float t = copysignf(1.f, tau) / (fabsf(tau) + sqrtf(1.f + tau*tau));
                c = rsqrtf(1.f + t*t);
                s = t * c;
            } else {
                c = 1.f; s = 0.f;
            }
            #pragma unroll
            for (int k = 0; k < 4; ++k) {
                float akp = Nm[k][p], akq = Nm[k][q];
                Nm[k][p] = c*akp - s*akq;
                Nm[k][q] = s*akp + c*akq;
            }
            #pragma unroll
            for (int k = 0; k < 4; ++k) {
                float apk = Nm[p][k], aqk = Nm[q][k];
                Nm[p][k] = c*apk - s*aqk;
                Nm[q][k] = s*apk + c*aqk;
            }
            #pragma unroll
            for (int k = 0; k < 4; ++k) {
                float vkp = Vv[k][p], vkq = Vv[k][q];
                Vv[k][p] = c*vkp - s*vkq;
                Vv[k][q] = s*vkp + c*vkq;
            }
        }
    }

    // pick eigenvector with max eigenvalue (constant indices via unroll + select)
    float q0=Vv[0][0], q1=Vv[1][0], q2=Vv[2][0], q3=Vv[3][0];
    float best = Nm[0][0];
    #pragma unroll
    for (int m = 1; m < 4; ++m) {
        bool bt = Nm[m][m] > best;
        best = bt ? Nm[m][m] : best;
        q0 = bt ? Vv[0][m] : q0;
        q1 = bt ? Vv[1][m] : q1;
        q2 = bt ? Vv[2][m] : q2;
        q3 = bt ? Vv[3][m] : q3;
    }
    float qn = rsqrtf(q0*q0 + q1*q1 + q2*q2 + q3*q3);
    q0*=qn; q1*=qn; q2*=qn; q3*=qn;

    float R00 = q0*q0+q1*q1-q2*q2-q3*q3;
    float R01 = 2.f*(q1*q2 - q0*q3);
    float R02 = 2.f*(q1*q3 + q0*q2);
    float R10 = 2.f*(q1*q2 + q0*q3);
    float R11 = q0*q0-q1*q1+q2*q2-q3*q3;
    float R12 = 2.f*(q2*q3 - q0*q1);
    float R20 = 2.f*(q1*q3 - q0*q2);
    float R21 = 2.f*(q2*q3 + q0*q1);
    float R22 = q0*q0-q1*q1-q2*q2+q3*q3;

    // convention safety: objective = tr(R H); if transpose scores higher, use it
    float trRH  = R00*H[0][0]+R01*H[1][0]+R02*H[2][0]
                + R10*H[0][1]+R11*H[1][1]+R12*H[2][1]
                + R20*H[0][2]+R21*H[1][2]+R22*H[2][2];
    float trRtH = R00*H[0][0]+R01*H[0][1]+R02*H[0][2]
                + R10*H[1][0]+R11*H[1][1]+R12*H[1][2]
                + R20*H[2][0]+R21*H[2][1]+R22*H[2][2];
    if (trRtH > trRH) {
        float t;
        t = R01; R01 = R10; R10 = t;
        t = R02; R02 = R20; R20 = t;
        t = R12; R12 = R21; R21 = t;
    }

    float t0 = cB0 - (R00*cA0 + R01*cA1 + R02*cA2);
    float t1 = cB1 - (R10*cA0 + R11*cA1 + R12*cA2);
    float t2 = cB2 - (R20*cA0 + R21*cA1 + R22*cA2);

    float4* O4 = reinterpret_cast<float4*>(Out + (size_t)b * 16);
    O4[0] = make_float4(R00, R01, R02, t0);
    O4[1] = make_float4(R10, R11, R12, t1);
    O4[2] = make_float4(R20, R21, R22, t2);
    O4[3] = make_float4(0.f, 0.f, 0.f, 1.f);
}

extern "C" void kernel_launch(void* const* d_in, const int* in_sizes, int n_in,
                              void* d_out, int out_size, void* d_ws, size_t ws_size,
                              hipStream_t stream) {
    const float* A = (const float*)d_in[0];
    const float* B = (const float*)d_in[1];
    const float* W = (const float*)d_in[2];
    float* Out = (float*)d_out;
    const int bs = out_size / 16;
    const int n  = (bs > 0) ? (in_sizes[2] / bs) : 0;
    const int threads = 256;
    const int blocks = (bs + threads - 1) / threads;
    hipLaunchKernelGGL(kabsch4x4_kernel, dim3(blocks), dim3(threads), 0, stream,
                       A, B, W, Out, bs, n);
}

// Round 4
// 157.121 us; speedup vs baseline: 1.0981x; 1.0981x over previous
//
#include <hip/hip_runtime.h>

#define EPS_W 1e-6f

// ---------------------------------------------------------------------------
// Shared solve: given the 17 weighted sums, produce R (3x3) and t (3).
// Horn quaternion method: build 4x4 N, Jacobi eigen-solve (5 sweeps,
// branchless fast rotations), take max-eigenvalue eigenvector.
// ---------------------------------------------------------------------------
__device__ __forceinline__ void solve_from_sums(
    float sw, float Sa0, float Sa1, float Sa2,
    float Sb0, float Sb1, float Sb2,
    float M00, float M01, float M02,
    float M10, float M11, float M12,
    float M20, float M21, float M22,
    float R[9], float t[3])
{
    const float inv = 1.f / (sw + EPS_W);
    const float cA0 = Sa0*inv, cA1 = Sa1*inv, cA2 = Sa2*inv;
    const float cB0 = Sb0*inv, cB1 = Sb1*inv, cB2 = Sb2*inv;

    float H[3][3];
    H[0][0] = M00 - cA0*Sb0 - Sa0*cB0 + sw*cA0*cB0;
    H[0][1] = M01 - cA0*Sb1 - Sa0*cB1 + sw*cA0*cB1;
    H[0][2] = M02 - cA0*Sb2 - Sa0*cB2 + sw*cA0*cB2;
    H[1][0] = M10 - cA1*Sb0 - Sa1*cB0 + sw*cA1*cB0;
    H[1][1] = M11 - cA1*Sb1 - Sa1*cB1 + sw*cA1*cB1;
    H[1][2] = M12 - cA1*Sb2 - Sa1*cB2 + sw*cA1*cB2;
    H[2][0] = M20 - cA2*Sb0 - Sa2*cB0 + sw*cA2*cB0;
    H[2][1] = M21 - cA2*Sb1 - Sa2*cB1 + sw*cA2*cB1;
    H[2][2] = M22 - cA2*Sb2 - Sa2*cB2 + sw*cA2*cB2;

    const float Sxx=H[0][0], Sxy=H[0][1], Sxz=H[0][2];
    const float Syx=H[1][0], Syy=H[1][1], Syz=H[1][2];
    const float Szx=H[2][0], Szy=H[2][1], Szz=H[2][2];

    float Nm[4][4];
    Nm[0][0] =  Sxx+Syy+Szz; Nm[0][1] = Syz-Szy;      Nm[0][2] = Szx-Sxz;      Nm[0][3] = Sxy-Syx;
    Nm[1][0] =  Nm[0][1];    Nm[1][1] = Sxx-Syy-Szz;  Nm[1][2] = Sxy+Syx;      Nm[1][3] = Szx+Sxz;
    Nm[2][0] =  Nm[0][2];    Nm[2][1] = Nm[1][2];     Nm[2][2] = -Sxx+Syy-Szz; Nm[2][3] = Syz+Szy;
    Nm[3][0] =  Nm[0][3];    Nm[3][1] = Nm[1][3];     Nm[3][2] = Nm[2][3];     Nm[3][3] = -Sxx-Syy+Szz;

    float Vv[4][4] = {{1.f,0.f,0.f,0.f},{0.f,1.f,0.f,0.f},{0.f,0.f,1.f,0.f},{0.f,0.f,0.f,1.f}};

    for (int sweep = 0; sweep < 5; ++sweep) {
        #pragma unroll
        for (int pair = 0; pair < 6; ++pair) {
            constexpr int PP[6] = {0,0,0,1,1,2};
            constexpr int QQ[6] = {1,2,3,2,3,3};
            const int p = PP[pair], q = QQ[pair];
            // branchless fast rotation: tan2t = 2*o/d annihilation, rsqrt-only.
            // verified equivalent to the tau/t/copysign formulation.
            float d  = Nm[p][p] - Nm[q][q];
            float o  = Nm[p][q];
            float r2 = d*d + 4.f*o*o;
            bool tiny = r2 < 1e-30f;
            float rinv = rsqrtf(tiny ? 1.f : r2);
            float hh = 0.5f + 0.5f * fabsf(d) * rinv;
            float ci = rsqrtf(hh);
            float c  = hh * ci;
            float s  = (d < 0.f ? o : -o) * rinv * ci;
            c = tiny ? 1.f : c;
            s = tiny ? 0.f : s;
            #pragma unroll
            for (int k = 0; k < 4; ++k) {
                float akp = Nm[k][p], akq = Nm[k][q];
                Nm[k][p] = c*akp - s*akq;
                Nm[k][q] = s*akp + c*akq;
            }
            #pragma unroll
            for (int k = 0; k < 4; ++k) {
                float apk = Nm[p][k], aqk = Nm[q][k];
                Nm[p][k] = c*apk - s*aqk;
                Nm[q][k] = s*apk + c*aqk;
            }
            #pragma unroll
            for (int k = 0; k < 4; ++k) {
                float vkp = Vv[k][p], vkq = Vv[k][q];
                Vv[k][p] = c*vkp - s*vkq;
                Vv[k][q] = s*vkp + c*vkq;
            }
        }
    }

    float q0=Vv[0][0], q1=Vv[1][0], q2=Vv[2][0], q3=Vv[3][0];
    float best = Nm[0][0];
    #pragma unroll
    for (int m = 1; m < 4; ++m) {
        bool bt = Nm[m][m] > best;
        best = bt ? Nm[m][m] : best;
        q0 = bt ? Vv[0][m] : q0;
        q1 = bt ? Vv[1][m] : q1;
        q2 = bt ? Vv[2][m] : q2;
        q3 = bt ? Vv[3][m] : q3;
    }
    float qn = rsqrtf(q0*q0 + q1*q1 + q2*q2 + q3*q3);
    q0*=qn; q1*=qn; q2*=qn; q3*=qn;

    float R00 = q0*q0+q1*q1-q2*q2-q3*q3;
    float R01 = 2.f*(q1*q2 - q0*q3);
    float R02 = 2.f*(q1*q3 + q0*q2);
    float R10 = 2.f*(q1*q2 + q0*q3);
    float R11 = q0*q0-q1*q1+q2*q2-q3*q3;
    float R12 = 2.f*(q2*q3 - q0*q1);
    float R20 = 2.f*(q1*q3 - q0*q2);
    float R21 = 2.f*(q2*q3 + q0*q1);
    float R22 = q0*q0-q1*q1-q2*q2+q3*q3;

    // convention guard: if tr(R^T H) beats tr(R H), transpose.
    float trRH  = R00*H[0][0]+R01*H[1][0]+R02*H[2][0]
                + R10*H[0][1]+R11*H[1][1]+R12*H[2][1]
                + R20*H[0][2]+R21*H[1][2]+R22*H[2][2];
    float trRtH = R00*H[0][0]+R01*H[0][1]+R02*H[0][2]
                + R10*H[1][0]+R11*H[1][1]+R12*H[1][2]
                + R20*H[2][0]+R21*H[2][1]+R22*H[2][2];
    if (trRtH > trRH) {
        float tt;
        tt = R01; R01 = R10; R10 = tt;
        tt = R02; R02 = R20; R20 = tt;
        tt = R12; R12 = R21; R21 = tt;
    }

    R[0]=R00; R[1]=R01; R[2]=R02;
    R[3]=R10; R[4]=R11; R[5]=R12;
    R[6]=R20; R[7]=R21; R[8]=R22;
    t[0] = cB0 - (R00*cA0 + R01*cA1 + R02*cA2);
    t[1] = cB1 - (R10*cA0 + R11*cA1 + R12*cA2);
    t[2] = cB2 - (R20*cA0 + R21*cA1 + R22*cA2);
}

// ---------------------------------------------------------------------------
// Fast path, n == 20: 2 threads per item. Each thread reads its contiguous
// 120B half-row as 15 aligned float2 (prompt full-line consumption -> ~1x
// fetch), accumulates 10 points, pair-combines via __shfl_xor(.,1), both
// lanes solve redundantly (no divergence), each stores 2 output rows.
// ---------------------------------------------------------------------------
__global__ __launch_bounds__(256) void kabsch_pair20_kernel(
    const float* __restrict__ A, const float* __restrict__ B,
    const float* __restrict__ W, float* __restrict__ Out, int bs)
{
    const int tid  = blockIdx.x * blockDim.x + threadIdx.x;
    const int item = tid >> 1;
    const int h    = tid & 1;
    if (item >= bs) return;

    const float2* A2 = reinterpret_cast<const float2*>(A);
    const float2* B2 = reinterpret_cast<const float2*>(B);
    const float2* W2 = reinterpret_cast<const float2*>(W);
    const int abase = item*30 + h*15;   // 30 float2 per item row (60 floats)
    const int wbase = item*10 + h*5;    // 10 float2 per item w-row (20 floats)

    float sw = 0.f;
    float Sa0=0.f,Sa1=0.f,Sa2=0.f, Sb0=0.f,Sb1=0.f,Sb2=0.f;
    float M00=0.f,M01=0.f,M02=0.f,M10=0.f,M11=0.f,M12=0.f,M20=0.f,M21=0.f,M22=0.f;

    #pragma unroll
    for (int g = 0; g < 5; ++g) {
        // 3 float2 = 6 floats = 2 points: p0=(a0.x,a0.y,a1.x), p1=(a1.y,a2.x,a2.y)
        float2 a0 = A2[abase+3*g+0], a1 = A2[abase+3*g+1], a2 = A2[abase+3*g+2];
        float2 b0 = B2[abase+3*g+0], b1 = B2[abase+3*g+1], b2 = B2[abase+3*g+2];
        float2 wv = W2[wbase+g];
        float w0 = wv.x < 0.f ? 0.f : wv.x;
        float w1 = wv.y < 0.f ? 0.f : wv.y;

        {   // point 0
            float ax=a0.x, ay=a0.y, az=a1.x;
            float bx=b0.x, by=b0.y, bz=b1.x;
            sw += w0;
            float wax=w0*ax, way=w0*ay, waz=w0*az;
            Sa0+=wax; Sa1+=way; Sa2+=waz;
            Sb0+=w0*bx; Sb1+=w0*by; Sb2+=w0*bz;
            M00+=wax*bx; M01+=wax*by; M02+=wax*bz;
            M10+=way*bx; M11+=way*by; M12+=way*bz;
            M20+=waz*bx; M21+=waz*by; M22+=waz*bz;
        }
        {   // point 1
            float ax=a1.y, ay=a2.x, az=a2.y;
            float bx=b1.y, by=b2.x, bz=b2.y;
            sw += w1;
            float wax=w1*ax, way=w1*ay, waz=w1*az;
            Sa0+=wax; Sa1+=way; Sa2+=waz;
            Sb0+=w1*bx; Sb1+=w1*by; Sb2+=w1*bz;
            M00+=wax*bx; M01+=wax*by; M02+=wax*bz;
            M10+=way*bx; M11+=way*by; M12+=way*bz;
            M20+=waz*bx; M21+=waz*by; M22+=waz*bz;
        }
    }

    // combine the two half-item partial sums (lanes 2i <-> 2i+1)
    sw  += __shfl_xor(sw, 1);
    Sa0 += __shfl_xor(Sa0,1); Sa1 += __shfl_xor(Sa1,1); Sa2 += __shfl_xor(Sa2,1);
    Sb0 += __shfl_xor(Sb0,1); Sb1 += __shfl_xor(Sb1,1); Sb2 += __shfl_xor(Sb2,1);
    M00 += __shfl_xor(M00,1); M01 += __shfl_xor(M01,1); M02 += __shfl_xor(M02,1);
    M10 += __shfl_xor(M10,1); M11 += __shfl_xor(M11,1); M12 += __shfl_xor(M12,1);
    M20 += __shfl_xor(M20,1); M21 += __shfl_xor(M21,1); M22 += __shfl_xor(M22,1);

    float R[9], t[3];
    solve_from_sums(sw,Sa0,Sa1,Sa2,Sb0,Sb1,Sb2,
                    M00,M01,M02,M10,M11,M12,M20,M21,M22, R, t);

    // each lane stores 2 of the 4 rows (branchless; wave writes contiguous)
    float4 va = h ? make_float4(R[6],R[7],R[8],t[2]) : make_float4(R[0],R[1],R[2],t[0]);
    float4 vb = h ? make_float4(0.f,0.f,0.f,1.f)     : make_float4(R[3],R[4],R[5],t[1]);
    float4* O4 = reinterpret_cast<float4*>(Out + (size_t)item * 16);
    O4[2*h]   = va;
    O4[2*h+1] = vb;
}

// ---------------------------------------------------------------------------
// Generic fallback (any n): 1 thread per item, scalar loads. (Previously
// validated structure.)
// ---------------------------------------------------------------------------
__global__ __launch_bounds__(256) void kabsch_generic_kernel(
    const float* __restrict__ A, const float* __restrict__ B,
    const float* __restrict__ W, float* __restrict__ Out,
    int bs, int n)
{
    const int b = blockIdx.x * blockDim.x + threadIdx.x;
    if (b >= bs) return;

    float sw = 0.f;
    float Sa0=0.f,Sa1=0.f,Sa2=0.f, Sb0=0.f,Sb1=0.f,Sb2=0.f;
    float M00=0.f,M01=0.f,M02=0.f,M10=0.f,M11=0.f,M12=0.f,M20=0.f,M21=0.f,M22=0.f;

    for (int j = 0; j < n; ++j) {
        const float* ap = A + ((size_t)b * n + j) * 3;
        const float* bp = B + ((size_t)b * n + j) * 3;
        float w = W[(size_t)b * n + j];
        w = w < 0.f ? 0.f : w;
        float ax=ap[0], ay=ap[1], az=ap[2];
        float bx=bp[0], by=bp[1], bz=bp[2];
        sw += w;
        float wax = w*ax, way = w*ay, waz = w*az;
        Sa0 += wax; Sa1 += way; Sa2 += waz;
        Sb0 += w*bx; Sb1 += w*by; Sb2 += w*bz;
        M00 += wax*bx; M01 += wax*by; M02 += wax*bz;
        M10 += way*bx; M11 += way*by; M12 += way*bz;
        M20 += waz*bx; M21 += waz*by; M22 += waz*bz;
    }

    float R[9], t[3];
    solve_from_sums(sw,Sa0,Sa1,Sa2,Sb0,Sb1,Sb2,
                    M00,M01,M02,M10,M11,M12,M20,M21,M22, R, t);

    float4* O4 = reinterpret_cast<float4*>(Out + (size_t)b * 16);
    O4[0] = make_float4(R[0], R[1], R[2], t[0]);
    O4[1] = make_float4(R[3], R[4], R[5], t[1]);
    O4[2] = make_float4(R[6], R[7], R[8], t[2]);
    O4[3] = make_float4(0.f, 0.f, 0.f, 1.f);
}

extern "C" void kernel_launch(void* const* d_in, const int* in_sizes, int n_in,
                              void* d_out, int out_size, void* d_ws, size_t ws_size,
                              hipStream_t stream) {
    const float* A = (const float*)d_in[0];
    const float* B = (const float*)d_in[1];
    const float* W = (const float*)d_in[2];
    float* Out = (float*)d_out;
    const int bs = out_size / 16;
    const int n  = (bs > 0) ? (in_sizes[2] / bs) : 0;
    const int threads = 256;
    if (n == 20) {
        const int total = bs * 2;
        const int blocks = (total + threads - 1) / threads;
        hipLaunchKernelGGL(kabsch_pair20_kernel, dim3(blocks), dim3(threads), 0, stream,
                           A, B, W, Out, bs);
    } else {
        const int blocks = (bs + threads - 1) / threads;
        hipLaunchKernelGGL(kabsch_generic_kernel, dim3(blocks), dim3(threads), 0, stream,
                           A, B, W, Out, bs, n);
    }
}

// Round 7
// 146.395 us; speedup vs baseline: 1.1785x; 1.0733x over previous
//
#include <hip/hip_runtime.h>

#define EPS_W 1e-6f

__device__ __forceinline__ float fast_rsq(float x) { return __builtin_amdgcn_rsqf(x); }
__device__ __forceinline__ float fast_rcp(float x) { return __builtin_amdgcn_rcpf(x); }

// ---------------------------------------------------------------------------
// Horn-quaternion solve via 5-sweep cyclic Jacobi on N (4x4).
// Math identical to HW-verified rounds 3/4 (absmax 0.0039); the ONLY change
// is rsqrtf/divide -> raw v_rsq_f32/v_rcp_f32 (libm's IEEE expansions were
// the hidden VALU cost; native instr err ~1e-7 << 3.4e-2 threshold).
// S[16] = { sw, Sa0..2, Sb0..2, M00,M01,M02,M10,M11,M12,M20,M21,M22 }
// ---------------------------------------------------------------------------
__device__ __forceinline__ void solve16(const float S[16], float R[9], float t[3])
{
    const float sw  = S[0];
    const float Sa0 = S[1], Sa1 = S[2], Sa2 = S[3];
    const float Sb0 = S[4], Sb1 = S[5], Sb2 = S[6];

    const float inv = fast_rcp(sw + EPS_W);
    const float cA0 = Sa0*inv, cA1 = Sa1*inv, cA2 = Sa2*inv;
    const float cB0 = Sb0*inv, cB1 = Sb1*inv, cB2 = Sb2*inv;

    float H[3][3];
    H[0][0] = S[7]  - cA0*Sb0 - Sa0*cB0 + sw*cA0*cB0;
    H[0][1] = S[8]  - cA0*Sb1 - Sa0*cB1 + sw*cA0*cB1;
    H[0][2] = S[9]  - cA0*Sb2 - Sa0*cB2 + sw*cA0*cB2;
    H[1][0] = S[10] - cA1*Sb0 - Sa1*cB0 + sw*cA1*cB0;
    H[1][1] = S[11] - cA1*Sb1 - Sa1*cB1 + sw*cA1*cB1;
    H[1][2] = S[12] - cA1*Sb2 - Sa1*cB2 + sw*cA1*cB2;
    H[2][0] = S[13] - cA2*Sb0 - Sa2*cB0 + sw*cA2*cB0;
    H[2][1] = S[14] - cA2*Sb1 - Sa2*cB1 + sw*cA2*cB1;
    H[2][2] = S[15] - cA2*Sb2 - Sa2*cB2 + sw*cA2*cB2;

    const float Sxx=H[0][0], Sxy=H[0][1], Sxz=H[0][2];
    const float Syx=H[1][0], Syy=H[1][1], Syz=H[1][2];
    const float Szx=H[2][0], Szy=H[2][1], Szz=H[2][2];

    float Nm[4][4];
    Nm[0][0] =  Sxx+Syy+Szz; Nm[0][1] = Syz-Szy;      Nm[0][2] = Szx-Sxz;      Nm[0][3] = Sxy-Syx;
    Nm[1][0] =  Nm[0][1];    Nm[1][1] = Sxx-Syy-Szz;  Nm[1][2] = Sxy+Syx;      Nm[1][3] = Szx+Sxz;
    Nm[2][0] =  Nm[0][2];    Nm[2][1] = Nm[1][2];     Nm[2][2] = -Sxx+Syy-Szz; Nm[2][3] = Syz+Szy;
    Nm[3][0] =  Nm[0][3];    Nm[3][1] = Nm[1][3];     Nm[3][2] = Nm[2][3];     Nm[3][3] = -Sxx-Syy+Szz;

    float Vv[4][4] = {{1.f,0.f,0.f,0.f},{0.f,1.f,0.f,0.f},{0.f,0.f,1.f,0.f},{0.f,0.f,0.f,1.f}};

    for (int sweep = 0; sweep < 5; ++sweep) {
        #pragma unroll
        for (int pair = 0; pair < 6; ++pair) {
            constexpr int PP[6] = {0,0,0,1,1,2};
            constexpr int QQ[6] = {1,2,3,2,3,3};
            const int p = PP[pair], q = QQ[pair];
            float d  = Nm[p][p] - Nm[q][q];
            float o  = Nm[p][q];
            float r2 = d*d + 4.f*o*o;
            bool tiny = r2 < 1e-30f;
            float rinv = fast_rsq(tiny ? 1.f : r2);
            float hh = 0.5f + 0.5f * fabsf(d) * rinv;
            float ci = fast_rsq(hh);
            float c  = hh * ci;
            float s  = (d < 0.f ? o : -o) * rinv * ci;
            c = tiny ? 1.f : c;
            s = tiny ? 0.f : s;
            #pragma unroll
            for (int k = 0; k < 4; ++k) {
                float akp = Nm[k][p], akq = Nm[k][q];
                Nm[k][p] = c*akp - s*akq;
                Nm[k][q] = s*akp + c*akq;
            }
            #pragma unroll
            for (int k = 0; k < 4; ++k) {
                float apk = Nm[p][k], aqk = Nm[q][k];
                Nm[p][k] = c*apk - s*aqk;
                Nm[q][k] = s*apk + c*aqk;
            }
            #pragma unroll
            for (int k = 0; k < 4; ++k) {
                float vkp = Vv[k][p], vkq = Vv[k][q];
                Vv[k][p] = c*vkp - s*vkq;
                Vv[k][q] = s*vkp + c*vkq;
            }
        }
    }

    float q0=Vv[0][0], q1=Vv[1][0], q2=Vv[2][0], q3=Vv[3][0];
    float best = Nm[0][0];
    #pragma unroll
    for (int m = 1; m < 4; ++m) {
        bool bt = Nm[m][m] > best;
        best = bt ? Nm[m][m] : best;
        q0 = bt ? Vv[0][m] : q0;
        q1 = bt ? Vv[1][m] : q1;
        q2 = bt ? Vv[2][m] : q2;
        q3 = bt ? Vv[3][m] : q3;
    }
    float qn = fast_rsq(q0*q0 + q1*q1 + q2*q2 + q3*q3);
    q0*=qn; q1*=qn; q2*=qn; q3*=qn;

    float R00 = q0*q0+q1*q1-q2*q2-q3*q3;
    float R01 = 2.f*(q1*q2 - q0*q3);
    float R02 = 2.f*(q1*q3 + q0*q2);
    float R10 = 2.f*(q1*q2 + q0*q3);
    float R11 = q0*q0-q1*q1+q2*q2-q3*q3;
    float R12 = 2.f*(q2*q3 - q0*q1);
    float R20 = 2.f*(q1*q3 - q0*q2);
    float R21 = 2.f*(q2*q3 + q0*q1);
    float R22 = q0*q0-q1*q1-q2*q2+q3*q3;

    // convention guard (HW-verified): transpose if tr(R^T H) > tr(R H)
    float trRH  = R00*Sxx+R01*Syx+R02*Szx
                + R10*Sxy+R11*Syy+R12*Szy
                + R20*Sxz+R21*Syz+R22*Szz;
    float trRtH = R00*Sxx+R01*Sxy+R02*Sxz
                + R10*Syx+R11*Syy+R12*Syz
                + R20*Szx+R21*Szy+R22*Szz;
    if (trRtH > trRH) {
        float tt;
        tt = R01; R01 = R10; R10 = tt;
        tt = R02; R02 = R20; R20 = tt;
        tt = R12; R12 = R21; R21 = tt;
    }

    R[0]=R00; R[1]=R01; R[2]=R02;
    R[3]=R10; R[4]=R11; R[5]=R12;
    R[6]=R20; R[7]=R21; R[8]=R22;
    t[0] = cB0 - (R00*cA0 + R01*cA1 + R02*cA2);
    t[1] = cB1 - (R10*cA0 + R11*cA1 + R12*cA2);
    t[2] = cB2 - (R20*cA0 + R21*cA1 + R22*cA2);
}

// ---------------------------------------------------------------------------
// Fused n==20 kernel, 256 threads / 128 items per block.
// Phase A: 2 threads/item accumulate (round-4-verified float2 path, ~1x
//          fetch), pair-combine via __shfl_xor(.,1), even lane -> LDS.
// Phase B: threads 0..127 solve ONE item each (waves 2,3 retire early ->
//          solve issue-cycles cut ~4x vs round 4's per-lane-redundant solve).
// ---------------------------------------------------------------------------
__global__ __launch_bounds__(256) void kabsch_fused20_kernel(
    const float* __restrict__ A, const float* __restrict__ B,
    const float* __restrict__ W, float* __restrict__ Out, int bs)
{
    __shared__ float sums[128][17];   // stride 17 (odd) -> conflict-free

    const int tid = threadIdx.x;
    const int blk = blockIdx.x;
    const int il  = tid >> 1;         // item within block, 0..127
    const int h   = tid & 1;
    int item = blk * 128 + il;
    int itemc = item < bs ? item : (bs - 1);   // clamp loads; stores guarded

    const float2* A2 = reinterpret_cast<const float2*>(A);
    const float2* B2 = reinterpret_cast<const float2*>(B);
    const float2* W2 = reinterpret_cast<const float2*>(W);
    const int abase = itemc*30 + h*15;
    const int wbase = itemc*10 + h*5;

    float sw = 0.f;
    float Sa0=0.f,Sa1=0.f,Sa2=0.f, Sb0=0.f,Sb1=0.f,Sb2=0.f;
    float M00=0.f,M01=0.f,M02=0.f,M10=0.f,M11=0.f,M12=0.f,M20=0.f,M21=0.f,M22=0.f;

    #pragma unroll
    for (int g = 0; g < 5; ++g) {
        float2 a0 = A2[abase+3*g+0], a1 = A2[abase+3*g+1], a2 = A2[abase+3*g+2];
        float2 b0 = B2[abase+3*g+0], b1 = B2[abase+3*g+1], b2 = B2[abase+3*g+2];
        float2 wv = W2[wbase+g];
        float w0 = wv.x < 0.f ? 0.f : wv.x;
        float w1 = wv.y < 0.f ? 0.f : wv.y;

        {   // point 0: (a0.x, a0.y, a1.x)
            float ax=a0.x, ay=a0.y, az=a1.x;
            float bx=b0.x, by=b0.y, bz=b1.x;
            sw += w0;
            float wax=w0*ax, way=w0*ay, waz=w0*az;
            Sa0+=wax; Sa1+=way; Sa2+=waz;
            Sb0+=w0*bx; Sb1+=w0*by; Sb2+=w0*bz;
            M00+=wax*bx; M01+=wax*by; M02+=wax*bz;
            M10+=way*bx; M11+=way*by; M12+=way*bz;
            M20+=waz*bx; M21+=waz*by; M22+=waz*bz;
        }
        {   // point 1: (a1.y, a2.x, a2.y)
            float ax=a1.y, ay=a2.x, az=a2.y;
            float bx=b1.y, by=b2.x, bz=b2.y;
            sw += w1;
            float wax=w1*ax, way=w1*ay, waz=w1*az;
            Sa0+=wax; Sa1+=way; Sa2+=waz;
            Sb0+=w1*bx; Sb1+=w1*by; Sb2+=w1*bz;
            M00+=wax*bx; M01+=wax*by; M02+=wax*bz;
            M10+=way*bx; M11+=way*by; M12+=way*bz;
            M20+=waz*bx; M21+=waz*by; M22+=waz*bz;
        }
    }

    // pair combine (lanes 2i <-> 2i+1)
    sw  += __shfl_xor(sw, 1);
    Sa0 += __shfl_xor(Sa0,1); Sa1 += __shfl_xor(Sa1,1); Sa2 += __shfl_xor(Sa2,1);
    Sb0 += __shfl_xor(Sb0,1); Sb1 += __shfl_xor(Sb1,1); Sb2 += __shfl_xor(Sb2,1);
    M00 += __shfl_xor(M00,1); M01 += __shfl_xor(M01,1); M02 += __shfl_xor(M02,1);
    M10 += __shfl_xor(M10,1); M11 += __shfl_xor(M11,1); M12 += __shfl_xor(M12,1);
    M20 += __shfl_xor(M20,1); M21 += __shfl_xor(M21,1); M22 += __shfl_xor(M22,1);

    if (h == 0) {
        sums[il][0]=sw;
        sums[il][1]=Sa0;  sums[il][2]=Sa1;  sums[il][3]=Sa2;
        sums[il][4]=Sb0;  sums[il][5]=Sb1;  sums[il][6]=Sb2;
        sums[il][7]=M00;  sums[il][8]=M01;  sums[il][9]=M02;
        sums[il][10]=M10; sums[il][11]=M11; sums[il][12]=M12;
        sums[il][13]=M20; sums[il][14]=M21; sums[il][15]=M22;
    }
    __syncthreads();

    if (tid < 128) {
        const int item2 = blk * 128 + tid;
        if (item2 < bs) {
            float S[16];
            #pragma unroll
            for (int k = 0; k < 16; ++k) S[k] = sums[tid][k];
            float R[9], t[3];
            solve16(S, R, t);
            float4* O4 = reinterpret_cast<float4*>(Out + (size_t)item2 * 16);
            O4[0] = make_float4(R[0], R[1], R[2], t[0]);
            O4[1] = make_float4(R[3], R[4], R[5], t[1]);
            O4[2] = make_float4(R[6], R[7], R[8], t[2]);
            O4[3] = make_float4(0.f, 0.f, 0.f, 1.f);
        }
    }
}

// ---------------------------------------------------------------------------
// Generic fallback (any n): 1 thread per item, scalar loads.
// ---------------------------------------------------------------------------
__global__ __launch_bounds__(256) void kabsch_generic_kernel(
    const float* __restrict__ A, const float* __restrict__ B,
    const float* __restrict__ W, float* __restrict__ Out,
    int bs, int n)
{
    const int b = blockIdx.x * blockDim.x + threadIdx.x;
    if (b >= bs) return;

    float S[16];
    #pragma unroll
    for (int k = 0; k < 16; ++k) S[k] = 0.f;

    for (int j = 0; j < n; ++j) {
        const float* ap = A + ((size_t)b * n + j) * 3;
        const float* bp = B + ((size_t)b * n + j) * 3;
        float w = W[(size_t)b * n + j];
        w = w < 0.f ? 0.f : w;
        float ax=ap[0], ay=ap[1], az=ap[2];
        float bx=bp[0], by=bp[1], bz=bp[2];
        S[0] += w;
        float wax = w*ax, way = w*ay, waz = w*az;
        S[1] += wax; S[2] += way; S[3] += waz;
        S[4] += w*bx; S[5] += w*by; S[6] += w*bz;
        S[7] += wax*bx; S[8]  += wax*by; S[9]  += wax*bz;
        S[10]+= way*bx; S[11] += way*by; S[12] += way*bz;
        S[13]+= waz*bx; S[14] += waz*by; S[15] += waz*bz;
    }

    float R[9], t[3];
    solve16(S, R, t);

    float4* O4 = reinterpret_cast<float4*>(Out + (size_t)b * 16);
    O4[0] = make_float4(R[0], R[1], R[2], t[0]);
    O4[1] = make_float4(R[3], R[4], R[5], t[1]);
    O4[2] = make_float4(R[6], R[7], R[8], t[2]);
    O4[3] = make_float4(0.f, 0.f, 0.f, 1.f);
}

extern "C" void kernel_launch(void* const* d_in, const int* in_sizes, int n_in,
                              void* d_out, int out_size, void* d_ws, size_t ws_size,
                              hipStream_t stream) {
    const float* A = (const float*)d_in[0];
    const float* B = (const float*)d_in[1];
    const float* W = (const float*)d_in[2];
    float* Out = (float*)d_out;
    const int bs = out_size / 16;
    const int n  = (bs > 0) ? (in_sizes[2] / bs) : 0;
    if (n == 20) {
        const int blocks = (bs + 127) / 128;
        hipLaunchKernelGGL(kabsch_fused20_kernel, dim3(blocks), dim3(256), 0, stream,
                           A, B, W, Out, bs);
    } else {
        const int blocks = (bs + 255) / 256;
        hipLaunchKernelGGL(kabsch_generic_kernel, dim3(blocks), dim3(256), 0, stream,
                           A, B, W, Out, bs, n);
    }
}